// Round 14
// baseline (613.457 us; speedup 1.0000x reference)
//
#include <hip/hip_runtime.h>
#include <hip/hip_fp16.h>

#define L_ 13
#define B_ 32
#define S_ 128
#define H_ 768
#define NU 32
#define GG 64
#define TU 96
#define LN_EPS 1e-3f
#define SEQ_ST 68      // seq LDS row stride (floats)
#define XT_ST 129      // xT2 row stride (half2 units) — odd => conflict-free
#define WK_ST 100      // wk2 row stride (half2 units per k2-row)
#define XPH_ST 100     // xp row stride (halves)
#define K1f 1.4426950408889634f   // log2(e)
#define K2f 2.8853900817779268f   // 2*log2(e)

// DPP controls
#define DPP_X1  0xB1
#define DPP_X2  0x4E
#define DPP_X7  0x141
#define DPP_X15 0x140

typedef float v2f __attribute__((ext_vector_type(2)));
typedef _Float16 h2t __attribute__((ext_vector_type(2)));
typedef unsigned int uv2 __attribute__((ext_vector_type(2)));

union F4H8 { float4 f4; __half2 hh[4]; h2t h[4]; };
union FH2  { float f; __half2 hh; h2t h; };
union F2H2 { float2 f2; __half2 hh[2]; };

__device__ __forceinline__ void pkfma(v2f& a, v2f x, v2f w) {
    asm("v_pk_fma_f32 %0, %1, %2, %0" : "+v"(a) : "v"(x), "v"(w));
}
template <int CTRL>
__device__ __forceinline__ float dppf(float x) {
    return __int_as_float(__builtin_amdgcn_update_dpp(
        0, __float_as_int(x), CTRL, 0xF, 0xF, true));
}
__device__ __forceinline__ float pairsum16(float x) {
#if __has_builtin(__builtin_amdgcn_permlane16_swap)
    uv2 s = __builtin_amdgcn_permlane16_swap(
        __float_as_uint(x), __float_as_uint(x), false, false);
    return __uint_as_float(s.x) + __uint_as_float(s.y);
#else
    return x + __shfl_xor(x, 16);
#endif
}
__device__ __forceinline__ void poll_ge_dev(unsigned* p, unsigned tgt) {
    int gd = 0;
    while (__hip_atomic_load(p, __ATOMIC_ACQUIRE, __HIP_MEMORY_SCOPE_AGENT) < tgt) {
        __builtin_amdgcn_s_sleep(2);
        if (++gd > (1 << 22)) break;
    }
}

// ===== fused: blocks 0-31 chain (R13-identical), blocks 32-447 lin producers =====
__global__ __launch_bounds__(512) void fused_kernel(
    const float* __restrict__ xs, const float* __restrict__ Wl,
    const float* __restrict__ bl,
    __half* __restrict__ lin_all, unsigned* __restrict__ lincnt,
    const float* __restrict__ Wr_f, const float* __restrict__ b_f,
    const float* __restrict__ Wr_b, const float* __restrict__ b_b,
    const float* __restrict__ Wk_f, const float* __restrict__ Wk_b,
    const float* __restrict__ ln_g, const float* __restrict__ ln_b,
    const float* __restrict__ W_cls, const float* __restrict__ b_cls,
    float* __restrict__ out)
{
    extern __shared__ float sm[];
    const int bid = blockIdx.x;
    const int t = threadIdx.x;

    if (bid >= B_) {
        // ================= LIN PRODUCER BLOCK: one (layer, batch) tile =================
        const int tix = bid - B_;          // 0..415
        const int l = tix >> 5;
        const int bb = tix & 31;
        const size_t row0 = (size_t)(l * B_ + bb) * S_;     // global row base
        __half2* sA2 = (__half2*)sm;                        // [32][132] half2 (k2 x row)
        __half2* sW2 = (__half2*)(sm + 32 * 132);           // [32][68]  half2 (k2 x col)

        const int rgrp = t & 31;
        const int cg = t >> 5;          // 0..15
        const int c0 = cg * 4;

        float acc[4][4];
        #pragma unroll
        for (int i = 0; i < 4; ++i)
            #pragma unroll
            for (int j = 0; j < 4; ++j) acc[i][j] = 0.f;

        for (int kt = 0; kt < H_; kt += 64) {
            #pragma unroll
            for (int i = 0; i < 4; ++i) {
                const int idx = t + 512 * i;
                const int r = idx >> 4, kq = idx & 15;
                float4 a = *(const float4*)&xs[(row0 + r) * H_ + kt + kq * 4];
                sA2[(2 * kq) * 132 + r]     = __floats2half2_rn(a.x, a.y);
                sA2[(2 * kq + 1) * 132 + r] = __floats2half2_rn(a.z, a.w);
            }
            {
                const int k2 = t >> 4, c4 = (t & 15) * 4;
                float4 w0 = *(const float4*)&Wl[(size_t)(kt + 2 * k2) * GG + c4];
                float4 w1 = *(const float4*)&Wl[(size_t)(kt + 2 * k2 + 1) * GG + c4];
                sW2[k2 * 68 + c4 + 0] = __floats2half2_rn(w0.x, w1.x);
                sW2[k2 * 68 + c4 + 1] = __floats2half2_rn(w0.y, w1.y);
                sW2[k2 * 68 + c4 + 2] = __floats2half2_rn(w0.z, w1.z);
                sW2[k2 * 68 + c4 + 3] = __floats2half2_rn(w0.w, w1.w);
            }
            __syncthreads();
            #pragma unroll 4
            for (int k2 = 0; k2 < 32; ++k2) {
                FH2 x0, x1, x2, x3;
                x0.hh = sA2[k2 * 132 + rgrp];
                x1.hh = sA2[k2 * 132 + rgrp + 32];
                x2.hh = sA2[k2 * 132 + rgrp + 64];
                x3.hh = sA2[k2 * 132 + rgrp + 96];
                F4H8 w; w.f4 = *(const float4*)&sW2[k2 * 68 + c0];
                #pragma unroll
                for (int m = 0; m < 4; ++m) {
                    acc[0][m] = __builtin_amdgcn_fdot2(x0.h, w.h[m], acc[0][m], false);
                    acc[1][m] = __builtin_amdgcn_fdot2(x1.h, w.h[m], acc[1][m], false);
                    acc[2][m] = __builtin_amdgcn_fdot2(x2.h, w.h[m], acc[2][m], false);
                    acc[3][m] = __builtin_amdgcn_fdot2(x3.h, w.h[m], acc[3][m], false);
                }
            }
            __syncthreads();
        }
        const float4 bv = *(const float4*)&bl[c0];
        #pragma unroll
        for (int i = 0; i < 4; ++i) {
            const int r = rgrp + 32 * i;
            F2H2 u;
            u.hh[0] = __floats2half2_rn(acc[i][0] + bv.x, acc[i][1] + bv.y);
            u.hh[1] = __floats2half2_rn(acc[i][2] + bv.z, acc[i][3] + bv.w);
            *(float2*)&lin_all[(row0 + r) * GG + c0] = u.f2;
        }
        __threadfence();
        __syncthreads();
        if (t == 0)
            __hip_atomic_fetch_add(&lincnt[l], 1u, __ATOMIC_RELEASE, __HIP_MEMORY_SCOPE_AGENT);
        return;
    }

    // ================= CHAIN BLOCK (R13-identical except per-layer lin poll) =================
    float*   seqb = sm;                                   // [128][SEQ_ST] f32
    __half2* xt2  = (__half2*)(sm + 8704);                // [32][XT_ST]
    __half2* wk2  = (__half2*)(sm + 8704 + 4128);         // [2][32][WK_ST] pre-scaled K1/K2
    __half*  xph  = (__half*)(sm + 8704 + 4128 + 6400);   // [2][128][XPH_ST]
    float*   hbf  = sm + 8704 + 4128 + 6400 + 12800;      // [32]
    float*   hbb  = hbf + NU;

    const int b = bid;
    const int wave = t >> 6;
    const int lane = t & 63;
    const int v16 = lane & 15;
    const int b4 = (lane >> 4) & 1;
    const int b5 = (lane >> 5) & 1;
    const int ud = v16 + 16 * b5;

    for (int i = t; i < S_ * SEQ_ST; i += 512) seqb[i] = 0.f;
    for (int i = t; i < 2 * 32 * 96; i += 512) {
        const int d = i / 3072, rem = i - d * 3072, k2 = rem / 96, c = rem - k2 * 96;
        const float* W = d ? Wk_b : Wk_f;
        const float sc = (c >= 64) ? K2f : K1f;
        wk2[(d * 32 + k2) * WK_ST + c] =
            __floats2half2_rn(W[(2 * k2) * TU + c] * sc, W[(2 * k2 + 1) * TU + c] * sc);
    }

    v2f wz[8], wr_[8], wh[8];
    float h_store = 0.f, h_dot = 0.f, rbz2 = 0.f, rbr2 = 0.f, rbh2 = 0.f;
    if (wave < 2) {
        const float* Wr   = wave ? Wr_b : Wr_f;
        const float* bias = wave ? b_b  : b_f;
        const int ex[8] = {0, 2, 7, 5, 15, 13, 8, 10};
        const int ey[8] = {1, 3, 6, 4, 14, 12, 9, 11};
        const int BB = 16 * b4;
        #pragma unroll
        for (int m = 0; m < 8; ++m) {
            const int jx = BB + (v16 ^ ex[m]), jy = BB + (v16 ^ ey[m]);
            wz[m]  = v2f{ K1f * Wr[jx * TU + ud],          K1f * Wr[jy * TU + ud] };
            wr_[m] = v2f{ K1f * Wr[jx * TU + NU + ud],     K1f * Wr[jy * TU + NU + ud] };
            wh[m]  = v2f{ K2f * Wr[jx * TU + 2 * NU + ud], K2f * Wr[jy * TU + 2 * NU + ud] };
        }
        rbz2 = 0.5f * K1f * bias[TU + ud];
        rbr2 = 0.5f * K1f * bias[TU + NU + ud];
        rbh2 = 0.5f * K2f * bias[TU + 2 * NU + ud];
    }

    const int g8 = t >> 3;
    const int c8 = (t & 7) << 3;
    const int rgrp = t & 31;
    const int cg = t >> 5;
    const int dsel = cg >> 3;
    const int cc = (cg & 7) * 12;
    const float* bias0 = dsel ? b_b : b_f;
    const __half2* wkd = wk2 + dsel * 32 * WK_ST;
    __half* xpd = xph + dsel * (S_ * XPH_ST);
    float bsc[12];
    #pragma unroll
    for (int m = 0; m < 12; ++m)
        bsc[m] = bias0[cc + m] * ((cc + m >= 64) ? K2f : K1f);

    __syncthreads();

    for (int l = 0; l < L_; ++l) {
        const __half* linb = lin_all + (size_t)(l * B_ + b) * S_ * GG;

        // wait for this layer's lin tiles (32 producer blocks)
        if (t == 0) poll_ge_dev(&lincnt[l], 32u);
        __syncthreads();

        // ---- phase 1: x = LN(lin + seq) -> fp16 k-pair transposed into xt2 ----
        #pragma unroll
        for (int p = 0; p < 2; ++p) {
            const int r = g8 + 64 * p;
            F4H8 lu; lu.f4 = *(const float4*)&linb[(size_t)r * GG + c8];
            float4 s0 = *(const float4*)&seqb[r * SEQ_ST + c8];
            float4 s1 = *(const float4*)&seqb[r * SEQ_ST + c8 + 4];
            float2 l0 = __half22float2(lu.hh[0]);
            float2 l1 = __half22float2(lu.hh[1]);
            float2 l2 = __half22float2(lu.hh[2]);
            float2 l3 = __half22float2(lu.hh[3]);
            float v[8];
            v[0] = l0.x + s0.x; v[1] = l0.y + s0.y; v[2] = l1.x + s0.z; v[3] = l1.y + s0.w;
            v[4] = l2.x + s1.x; v[5] = l2.y + s1.y; v[6] = l3.x + s1.z; v[7] = l3.y + s1.w;
            float s = 0.f;
            #pragma unroll
            for (int j = 0; j < 8; ++j) s += v[j];
            #pragma unroll
            for (int off = 1; off < 8; off <<= 1) s += __shfl_xor(s, off);
            const float mean = s * 0.015625f;
            float q = 0.f;
            float d[8];
            #pragma unroll
            for (int j = 0; j < 8; ++j) { d[j] = v[j] - mean; q += d[j] * d[j]; }
            #pragma unroll
            for (int off = 1; off < 8; off <<= 1) q += __shfl_xor(q, off);
            const float rstd = rsqrtf(q * 0.015625f + LN_EPS);
            float4 g0 = *(const float4*)&ln_g[c8];
            float4 g1 = *(const float4*)&ln_g[c8 + 4];
            float4 b0 = *(const float4*)&ln_b[c8];
            float4 b1 = *(const float4*)&ln_b[c8 + 4];
            float x[8];
            x[0] = d[0] * rstd * g0.x + b0.x; x[1] = d[1] * rstd * g0.y + b0.y;
            x[2] = d[2] * rstd * g0.z + b0.z; x[3] = d[3] * rstd * g0.w + b0.w;
            x[4] = d[4] * rstd * g1.x + b1.x; x[5] = d[5] * rstd * g1.y + b1.y;
            x[6] = d[6] * rstd * g1.z + b1.z; x[7] = d[7] * rstd * g1.w + b1.w;
            #pragma unroll
            for (int j = 0; j < 4; ++j)
                xt2[(c8 / 2 + j) * XT_ST + r] = __floats2half2_rn(x[2 * j], x[2 * j + 1]);
        }
        __syncthreads();

        // ---- phase 2: xp = x @ Wk(K-scaled) + bias(K-scaled) via v_dot2_f32_f16 ----
        {
            float acc[4][12];
            #pragma unroll
            for (int m = 0; m < 12; ++m) {
                acc[0][m] = bsc[m]; acc[1][m] = bsc[m]; acc[2][m] = bsc[m]; acc[3][m] = bsc[m];
            }
            #pragma unroll 4
            for (int k2 = 0; k2 < 32; ++k2) {
                FH2 x0, x1, x2, x3;
                x0.hh = xt2[k2 * XT_ST + rgrp];
                x1.hh = xt2[k2 * XT_ST + rgrp + 32];
                x2.hh = xt2[k2 * XT_ST + rgrp + 64];
                x3.hh = xt2[k2 * XT_ST + rgrp + 96];
                F4H8 wa, wb, wc;
                wa.f4 = *(const float4*)&wkd[k2 * WK_ST + cc];
                wb.f4 = *(const float4*)&wkd[k2 * WK_ST + cc + 4];
                wc.f4 = *(const float4*)&wkd[k2 * WK_ST + cc + 8];
                #pragma unroll
                for (int m = 0; m < 4; ++m) {
                    acc[0][m]     = __builtin_amdgcn_fdot2(x0.h, wa.h[m], acc[0][m],     false);
                    acc[1][m]     = __builtin_amdgcn_fdot2(x1.h, wa.h[m], acc[1][m],     false);
                    acc[2][m]     = __builtin_amdgcn_fdot2(x2.h, wa.h[m], acc[2][m],     false);
                    acc[3][m]     = __builtin_amdgcn_fdot2(x3.h, wa.h[m], acc[3][m],     false);
                    acc[0][m + 4] = __builtin_amdgcn_fdot2(x0.h, wb.h[m], acc[0][m + 4], false);
                    acc[1][m + 4] = __builtin_amdgcn_fdot2(x1.h, wb.h[m], acc[1][m + 4], false);
                    acc[2][m + 4] = __builtin_amdgcn_fdot2(x2.h, wb.h[m], acc[2][m + 4], false);
                    acc[3][m + 4] = __builtin_amdgcn_fdot2(x3.h, wb.h[m], acc[3][m + 4], false);
                    acc[0][m + 8] = __builtin_amdgcn_fdot2(x0.h, wc.h[m], acc[0][m + 8], false);
                    acc[1][m + 8] = __builtin_amdgcn_fdot2(x1.h, wc.h[m], acc[1][m + 8], false);
                    acc[2][m + 8] = __builtin_amdgcn_fdot2(x2.h, wc.h[m], acc[2][m + 8], false);
                    acc[3][m + 8] = __builtin_amdgcn_fdot2(x3.h, wc.h[m], acc[3][m + 8], false);
                }
            }
            #pragma unroll
            for (int i = 0; i < 4; ++i) {
                const int r = rgrp + 32 * i;
                __half2* dst = (__half2*)&xpd[r * XPH_ST + cc];
                #pragma unroll
                for (int j = 0; j < 6; ++j)
                    dst[j] = __floats2half2_rn(acc[i][2 * j], acc[i][2 * j + 1]);
            }
        }
        __syncthreads();

        // ---- phase 3: half-dot scan (two waves, separate SIMDs); exp2/rcp gates ----
        if (wave < 2) {
            const int dir = wave;
            const __half* xp = xph + dir * (S_ * XPH_ST);
            float* sq = seqb + dir * NU + (lane & 31);
            const int stp = dir ? -1 : 1;
            int s = dir ? (S_ - 1) : 0;
            const bool wl = (lane < 32);
            const bool fix = (b4 != b5);
            float xz = (float)xp[s * XPH_ST + ud];
            float xr = (float)xp[s * XPH_ST + 32 + ud];
            float xh = (float)xp[s * XPH_ST + 64 + ud];
            for (int st = 0; st < S_; ++st) {
                float nz = 0.f, nr = 0.f, nh = 0.f;
                if (st < S_ - 1) {
                    const int sn = s + stp;
                    nz = (float)xp[sn * XPH_ST + ud];
                    nr = (float)xp[sn * XPH_ST + 32 + ud];
                    nh = (float)xp[sn * XPH_ST + 64 + ud];
                }
                v2f ro[8];
                ro[0].x = h_store;                ro[0].y = dppf<DPP_X1>(h_store);
                ro[1].x = dppf<DPP_X2>(ro[0].x);  ro[1].y = dppf<DPP_X2>(ro[0].y);
                ro[2].x = dppf<DPP_X7>(ro[0].x);  ro[2].y = dppf<DPP_X7>(ro[0].y);
                ro[3].x = dppf<DPP_X7>(ro[1].x);  ro[3].y = dppf<DPP_X7>(ro[1].y);
                ro[4].x = dppf<DPP_X15>(ro[0].x); ro[4].y = dppf<DPP_X15>(ro[0].y);
                ro[5].x = dppf<DPP_X15>(ro[1].x); ro[5].y = dppf<DPP_X15>(ro[1].y);
                ro[6].x = dppf<DPP_X15>(ro[2].x); ro[6].y = dppf<DPP_X15>(ro[2].y);
                ro[7].x = dppf<DPP_X15>(ro[3].x); ro[7].y = dppf<DPP_X15>(ro[3].y);

                v2f aza = v2f{0.5f * xz + rbz2, 0.f}, azb = v2f{0.f, 0.f};
                v2f ara = v2f{0.5f * xr + rbr2, 0.f}, arb = v2f{0.f, 0.f};
                v2f aha = v2f{rbh2, 0.f},             ahb = v2f{0.f, 0.f};
                #pragma unroll
                for (int m = 0; m < 4; ++m) {
                    pkfma(aza, ro[m], wz[m]);      pkfma(azb, ro[m + 4], wz[m + 4]);
                    pkfma(ara, ro[m], wr_[m]);     pkfma(arb, ro[m + 4], wr_[m + 4]);
                    pkfma(aha, ro[m], wh[m]);      pkfma(ahb, ro[m + 4], wh[m + 4]);
                }
                v2f azs = aza + azb, ars = ara + arb, ahs = aha + ahb;
                const float pz = pairsum16(azs.x + azs.y);
                const float pr = pairsum16(ars.x + ars.y);
                const float ph = pairsum16(ahs.x + ahs.y);

                const float z  = __builtin_amdgcn_rcpf(1.0f + __builtin_amdgcn_exp2f(-pz));
                const float r  = __builtin_amdgcn_rcpf(1.0f + __builtin_amdgcn_exp2f(-pr));
                const float tt = xh + r * ph;
                const float et = __builtin_amdgcn_exp2f(-tt);
                const float hh = (1.0f - et) * __builtin_amdgcn_rcpf(1.0f + et);
                const float hn_raw = hh + z * (h_dot - hh);
                h_dot = hn_raw;
                uv2 s32 = __builtin_amdgcn_permlane32_swap(
                    __float_as_uint(hn_raw), __float_as_uint(hn_raw), false, false);
                const float v32 = wl ? __uint_as_float(s32.y) : __uint_as_float(s32.x);
                h_store = fix ? v32 : hn_raw;
                if (wl) sq[s * SEQ_ST] = h_store;
                s += stp; xz = nz; xr = nr; xh = nh;
            }
        }
        __syncthreads();
    }

    // ---- final h + classifier ----
    if (wave < 2 && lane < 32) (wave ? hbb : hbf)[lane & 31] = h_store;
    __syncthreads();
    if (t == 0) {
        float l0 = b_cls[0], l1 = b_cls[1];
        for (int j = 0; j < NU; ++j) {
            const float hf = hbf[j], hk = hbb[j];
            l0 += hf * W_cls[4 * j]     + hk * W_cls[4 * j + 2];
            l1 += hf * W_cls[4 * j + 1] + hk * W_cls[4 * j + 3];
        }
        const float m = fmaxf(l0, l1);
        const float e0 = __expf(l0 - m), e1 = __expf(l1 - m);
        const float inv = 1.0f / (e0 + e1);
        out[b * 2 + 0] = e0 * inv;
        out[b * 2 + 1] = e1 * inv;
    }
}

extern "C" void kernel_launch(void* const* d_in, const int* in_sizes, int n_in,
                              void* d_out, int out_size, void* d_ws, size_t ws_size,
                              hipStream_t stream) {
    const float* xs    = (const float*)d_in[0];
    const float* W_lin = (const float*)d_in[1];
    const float* b_lin = (const float*)d_in[2];
    const float* ln_g  = (const float*)d_in[3];
    const float* ln_b  = (const float*)d_in[4];
    const float* Wk_f  = (const float*)d_in[5];
    const float* Wr_f  = (const float*)d_in[6];
    const float* b_f   = (const float*)d_in[7];
    const float* Wk_b  = (const float*)d_in[8];
    const float* Wr_b  = (const float*)d_in[9];
    const float* b_b   = (const float*)d_in[10];
    const float* W_cls = (const float*)d_in[11];
    const float* b_cls = (const float*)d_in[12];
    float* out = (float*)d_out;

    char* ws = (char*)d_ws;
    __half* lin_all = (__half*)ws;                         // 13*4096*64 fp16 = 6,815,744 B
    unsigned* lincnt = (unsigned*)(ws + 6815744);          // 13 counters

    hipMemsetAsync(lincnt, 0, 64, stream);

    // floats: seqb 8704 + xt2 4128 + wk2 6400 + xph 12800 + hb 64 = 32,096 -> 128,384 B
    const int smem = (8704 + 4128 + 6400 + 12800 + 64) * (int)sizeof(float);
    (void)hipFuncSetAttribute((const void*)fused_kernel,
                              hipFuncAttributeMaxDynamicSharedMemorySize, smem);

    fused_kernel<<<B_ + L_ * B_, 512, smem, stream>>>(
        xs, W_lin, b_lin, lin_all, lincnt,
        Wr_f, b_f, Wr_b, b_b, Wk_f, Wk_b, ln_g, ln_b, W_cls, b_cls, out);
}

// Round 15
// 587.706 us; speedup vs baseline: 1.0438x; 1.0438x over previous
//
#include <hip/hip_runtime.h>
#include <hip/hip_fp16.h>

#define L_ 13
#define B_ 32
#define S_ 128
#define H_ 768
#define NU 32
#define GG 64
#define TU 96
#define LN_EPS 1e-3f
#define SEQ_ST 68      // seq LDS row stride (floats)
#define XT_ST 129      // xT2 row stride (half2 units) — odd => conflict-free
#define WK_ST 100      // wk2 row stride (half2 units per k2-row)
#define XPH_ST 100     // xp row stride (halves)
#define K1f 1.4426950408889634f   // log2(e)
#define K2f 2.8853900817779268f   // 2*log2(e)

// DPP controls
#define DPP_X1  0xB1
#define DPP_X2  0x4E
#define DPP_X7  0x141
#define DPP_X15 0x140

typedef float v2f __attribute__((ext_vector_type(2)));
typedef _Float16 h2t __attribute__((ext_vector_type(2)));
typedef unsigned int uv2 __attribute__((ext_vector_type(2)));

union F4H8 { float4 f4; __half2 hh[4]; h2t h[4]; };
union FH2  { float f; __half2 hh; h2t h; };
union F2H2 { float2 f2; __half2 hh[2]; };

__device__ __forceinline__ void pkfma(v2f& a, v2f x, v2f w) {
    asm("v_pk_fma_f32 %0, %1, %2, %0" : "+v"(a) : "v"(x), "v"(w));
}
template <int CTRL>
__device__ __forceinline__ float dppf(float x) {
    return __int_as_float(__builtin_amdgcn_update_dpp(
        0, __float_as_int(x), CTRL, 0xF, 0xF, true));
}
__device__ __forceinline__ float pairsum16(float x) {
#if __has_builtin(__builtin_amdgcn_permlane16_swap)
    uv2 s = __builtin_amdgcn_permlane16_swap(
        __float_as_uint(x), __float_as_uint(x), false, false);
    return __uint_as_float(s.x) + __uint_as_float(s.y);
#else
    return x + __shfl_xor(x, 16);
#endif
}

// ------- lin2: xs @ W_lin + b_lin (fp16 out), fdot2-based, 128-row tiles, 416 blocks -------
__global__ __launch_bounds__(512) void lin2_kernel(
    const float* __restrict__ xs, const float* __restrict__ Wl,
    const float* __restrict__ bl, __half* __restrict__ lin_all)
{
    __shared__ __half2 sA2[32 * 132];   // [k2][row] (132 stride, conflict-free)
    __shared__ __half2 sW2[32 * 68];    // [k2][col pairs of k]

    const int tix = blockIdx.x;         // 0..415 = (layer, batch) tile
    const size_t row0 = (size_t)tix * S_;
    const int t = threadIdx.x;
    const int rgrp = t & 31;
    const int cg = t >> 5;              // 0..15
    const int c0 = cg * 4;

    float acc[4][4];
    #pragma unroll
    for (int i = 0; i < 4; ++i)
        #pragma unroll
        for (int j = 0; j < 4; ++j) acc[i][j] = 0.f;

    for (int kt = 0; kt < H_; kt += 64) {
        #pragma unroll
        for (int i = 0; i < 4; ++i) {
            const int idx = t + 512 * i;
            const int r = idx >> 4, kq = idx & 15;
            float4 a = *(const float4*)&xs[(row0 + r) * H_ + kt + kq * 4];
            sA2[(2 * kq) * 132 + r]     = __floats2half2_rn(a.x, a.y);
            sA2[(2 * kq + 1) * 132 + r] = __floats2half2_rn(a.z, a.w);
        }
        {
            const int k2 = t >> 4, c4 = (t & 15) * 4;
            float4 w0 = *(const float4*)&Wl[(size_t)(kt + 2 * k2) * GG + c4];
            float4 w1 = *(const float4*)&Wl[(size_t)(kt + 2 * k2 + 1) * GG + c4];
            sW2[k2 * 68 + c4 + 0] = __floats2half2_rn(w0.x, w1.x);
            sW2[k2 * 68 + c4 + 1] = __floats2half2_rn(w0.y, w1.y);
            sW2[k2 * 68 + c4 + 2] = __floats2half2_rn(w0.z, w1.z);
            sW2[k2 * 68 + c4 + 3] = __floats2half2_rn(w0.w, w1.w);
        }
        __syncthreads();
        #pragma unroll 4
        for (int k2 = 0; k2 < 32; ++k2) {
            FH2 x0, x1, x2, x3;
            x0.hh = sA2[k2 * 132 + rgrp];
            x1.hh = sA2[k2 * 132 + rgrp + 32];
            x2.hh = sA2[k2 * 132 + rgrp + 64];
            x3.hh = sA2[k2 * 132 + rgrp + 96];
            F4H8 w; w.f4 = *(const float4*)&sW2[k2 * 68 + c0];
            #pragma unroll
            for (int m = 0; m < 4; ++m) {
                acc[0][m] = __builtin_amdgcn_fdot2(x0.h, w.h[m], acc[0][m], false);
                acc[1][m] = __builtin_amdgcn_fdot2(x1.h, w.h[m], acc[1][m], false);
                acc[2][m] = __builtin_amdgcn_fdot2(x2.h, w.h[m], acc[2][m], false);
                acc[3][m] = __builtin_amdgcn_fdot2(x3.h, w.h[m], acc[3][m], false);
            }
        }
        __syncthreads();
    }
    const float4 bv = *(const float4*)&bl[c0];
    #pragma unroll
    for (int i = 0; i < 4; ++i) {
        const int r = rgrp + 32 * i;
        F2H2 u;
        u.hh[0] = __floats2half2_rn(acc[i][0] + bv.x, acc[i][1] + bv.y);
        u.hh[1] = __floats2half2_rn(acc[i][2] + bv.z, acc[i][3] + bv.w);
        *(float2*)&lin_all[(row0 + r) * GG + c0] = u.f2;
    }
}

// ---------------- one block per batch: 13 x (LN + xp + bidir GRU scan) + classifier ----------------
__global__ __launch_bounds__(512) void chain_kernel(
    const __half* __restrict__ lin_all,
    const float* __restrict__ Wr_f, const float* __restrict__ b_f,
    const float* __restrict__ Wr_b, const float* __restrict__ b_b,
    const float* __restrict__ Wk_f, const float* __restrict__ Wk_b,
    const float* __restrict__ ln_g, const float* __restrict__ ln_b,
    const float* __restrict__ W_cls, const float* __restrict__ b_cls,
    float* __restrict__ out)
{
    extern __shared__ float sm[];
    float*   seqb = sm;                                   // [128][SEQ_ST] f32
    __half2* xt2  = (__half2*)(sm + 8704);                // [32][XT_ST]  x, k-pairs
    __half2* wk2  = (__half2*)(sm + 8704 + 4128);         // [2][32][WK_ST] pre-scaled K1/K2
    __half*  xph  = (__half*)(sm + 8704 + 4128 + 6400);   // [2][128][XPH_ST] pre-scaled
    float*   hbf  = sm + 8704 + 4128 + 6400 + 12800;      // [32]
    float*   hbb  = hbf + NU;

    const int b = blockIdx.x;
    const int t = threadIdx.x;
    const int wave = t >> 6;
    const int lane = t & 63;
    const int v16 = lane & 15;
    const int b4 = (lane >> 4) & 1;
    const int b5 = (lane >> 5) & 1;
    const int ud = v16 + 16 * b5;      // unit this lane's dot computes

    for (int i = t; i < S_ * SEQ_ST; i += 512) seqb[i] = 0.f;
    // stage Wk (layer-invariant) into LDS with gate scaling folded (z,r: K1; h: K2)
    for (int i = t; i < 2 * 32 * 96; i += 512) {
        const int d = i / 3072, rem = i - d * 3072, k2 = rem / 96, c = rem - k2 * 96;
        const float* W = d ? Wk_b : Wk_f;
        const float sc = (c >= 64) ? K2f : K1f;
        wk2[(d * 32 + k2) * WK_ST + c] =
            __floats2half2_rn(W[(2 * k2) * TU + c] * sc, W[(2 * k2 + 1) * TU + c] * sc);
    }

    // ---- scan-wave persistent state (waves 0=fwd, 1=bwd): row-half weight columns, K-scaled ----
    v2f wz[8], wr_[8], wh[8];
    float h_store = 0.f, h_dot = 0.f, rbz2 = 0.f, rbr2 = 0.f, rbh2 = 0.f;
    if (wave < 2) {
        const float* Wr   = wave ? Wr_b : Wr_f;
        const float* bias = wave ? b_b  : b_f;
        const int ex[8] = {0, 2, 7, 5, 15, 13, 8, 10};
        const int ey[8] = {1, 3, 6, 4, 14, 12, 9, 11};
        const int BB = 16 * b4;        // h-range this lane dots over
        #pragma unroll
        for (int m = 0; m < 8; ++m) {
            const int jx = BB + (v16 ^ ex[m]), jy = BB + (v16 ^ ey[m]);
            wz[m]  = v2f{ K1f * Wr[jx * TU + ud],          K1f * Wr[jy * TU + ud] };
            wr_[m] = v2f{ K1f * Wr[jx * TU + NU + ud],     K1f * Wr[jy * TU + NU + ud] };
            wh[m]  = v2f{ K2f * Wr[jx * TU + 2 * NU + ud], K2f * Wr[jy * TU + 2 * NU + ud] };
        }
        // halve: bias/x-init added by BOTH l^16 partners, then pair-summed
        rbz2 = 0.5f * K1f * bias[TU + ud];
        rbr2 = 0.5f * K1f * bias[TU + NU + ud];
        rbh2 = 0.5f * K2f * bias[TU + 2 * NU + ud];
    }

    // phase-1 mapping: 8-lane LN groups, 8 cols each, 2 passes
    const int g8 = t >> 3;
    const int c8 = (t & 7) << 3;
    // phase-2 mapping
    const int rgrp = t & 31;
    const int cg = t >> 5;
    const int dsel = cg >> 3;
    const int cc = (cg & 7) * 12;
    const float* bias0 = dsel ? b_b : b_f;
    const __half2* wkd = wk2 + dsel * 32 * WK_ST;
    __half* xpd = xph + dsel * (S_ * XPH_ST);
    float bsc[12];
    #pragma unroll
    for (int m = 0; m < 12; ++m)
        bsc[m] = bias0[cc + m] * ((cc + m >= 64) ? K2f : K1f);

    __syncthreads();

    for (int l = 0; l < L_; ++l) {
        const __half* linb = lin_all + (size_t)(l * B_ + b) * S_ * GG;

        // ---- phase 1: x = LN(lin + seq) -> fp16 k-pair transposed into xt2 ----
        #pragma unroll
        for (int p = 0; p < 2; ++p) {
            const int r = g8 + 64 * p;
            F4H8 lu; lu.f4 = *(const float4*)&linb[(size_t)r * GG + c8];
            float4 s0 = *(const float4*)&seqb[r * SEQ_ST + c8];
            float4 s1 = *(const float4*)&seqb[r * SEQ_ST + c8 + 4];
            float2 l0 = __half22float2(lu.hh[0]);
            float2 l1 = __half22float2(lu.hh[1]);
            float2 l2 = __half22float2(lu.hh[2]);
            float2 l3 = __half22float2(lu.hh[3]);
            float v[8];
            v[0] = l0.x + s0.x; v[1] = l0.y + s0.y; v[2] = l1.x + s0.z; v[3] = l1.y + s0.w;
            v[4] = l2.x + s1.x; v[5] = l2.y + s1.y; v[6] = l3.x + s1.z; v[7] = l3.y + s1.w;
            float s = 0.f;
            #pragma unroll
            for (int j = 0; j < 8; ++j) s += v[j];
            #pragma unroll
            for (int off = 1; off < 8; off <<= 1) s += __shfl_xor(s, off);
            const float mean = s * 0.015625f;
            float q = 0.f;
            float d[8];
            #pragma unroll
            for (int j = 0; j < 8; ++j) { d[j] = v[j] - mean; q += d[j] * d[j]; }
            #pragma unroll
            for (int off = 1; off < 8; off <<= 1) q += __shfl_xor(q, off);
            const float rstd = rsqrtf(q * 0.015625f + LN_EPS);
            float4 g0 = *(const float4*)&ln_g[c8];
            float4 g1 = *(const float4*)&ln_g[c8 + 4];
            float4 b0 = *(const float4*)&ln_b[c8];
            float4 b1 = *(const float4*)&ln_b[c8 + 4];
            float x[8];
            x[0] = d[0] * rstd * g0.x + b0.x; x[1] = d[1] * rstd * g0.y + b0.y;
            x[2] = d[2] * rstd * g0.z + b0.z; x[3] = d[3] * rstd * g0.w + b0.w;
            x[4] = d[4] * rstd * g1.x + b1.x; x[5] = d[5] * rstd * g1.y + b1.y;
            x[6] = d[6] * rstd * g1.z + b1.z; x[7] = d[7] * rstd * g1.w + b1.w;
            #pragma unroll
            for (int j = 0; j < 4; ++j)
                xt2[(c8 / 2 + j) * XT_ST + r] = __floats2half2_rn(x[2 * j], x[2 * j + 1]);
        }
        __syncthreads();

        // ---- phase 2: xp = x @ Wk(K-scaled) + bias(K-scaled) via v_dot2_f32_f16 ----
        {
            float acc[4][12];
            #pragma unroll
            for (int m = 0; m < 12; ++m) {
                acc[0][m] = bsc[m]; acc[1][m] = bsc[m]; acc[2][m] = bsc[m]; acc[3][m] = bsc[m];
            }
            #pragma unroll 4
            for (int k2 = 0; k2 < 32; ++k2) {
                FH2 x0, x1, x2, x3;
                x0.hh = xt2[k2 * XT_ST + rgrp];
                x1.hh = xt2[k2 * XT_ST + rgrp + 32];
                x2.hh = xt2[k2 * XT_ST + rgrp + 64];
                x3.hh = xt2[k2 * XT_ST + rgrp + 96];
                F4H8 wa, wb, wc;
                wa.f4 = *(const float4*)&wkd[k2 * WK_ST + cc];
                wb.f4 = *(const float4*)&wkd[k2 * WK_ST + cc + 4];
                wc.f4 = *(const float4*)&wkd[k2 * WK_ST + cc + 8];
                #pragma unroll
                for (int m = 0; m < 4; ++m) {
                    acc[0][m]     = __builtin_amdgcn_fdot2(x0.h, wa.h[m], acc[0][m],     false);
                    acc[1][m]     = __builtin_amdgcn_fdot2(x1.h, wa.h[m], acc[1][m],     false);
                    acc[2][m]     = __builtin_amdgcn_fdot2(x2.h, wa.h[m], acc[2][m],     false);
                    acc[3][m]     = __builtin_amdgcn_fdot2(x3.h, wa.h[m], acc[3][m],     false);
                    acc[0][m + 4] = __builtin_amdgcn_fdot2(x0.h, wb.h[m], acc[0][m + 4], false);
                    acc[1][m + 4] = __builtin_amdgcn_fdot2(x1.h, wb.h[m], acc[1][m + 4], false);
                    acc[2][m + 4] = __builtin_amdgcn_fdot2(x2.h, wb.h[m], acc[2][m + 4], false);
                    acc[3][m + 4] = __builtin_amdgcn_fdot2(x3.h, wb.h[m], acc[3][m + 4], false);
                    acc[0][m + 8] = __builtin_amdgcn_fdot2(x0.h, wc.h[m], acc[0][m + 8], false);
                    acc[1][m + 8] = __builtin_amdgcn_fdot2(x1.h, wc.h[m], acc[1][m + 8], false);
                    acc[2][m + 8] = __builtin_amdgcn_fdot2(x2.h, wc.h[m], acc[2][m + 8], false);
                    acc[3][m + 8] = __builtin_amdgcn_fdot2(x3.h, wc.h[m], acc[3][m + 8], false);
                }
            }
            #pragma unroll
            for (int i = 0; i < 4; ++i) {
                const int r = rgrp + 32 * i;
                __half2* dst = (__half2*)&xpd[r * XPH_ST + cc];
                #pragma unroll
                for (int j = 0; j < 6; ++j)
                    dst[j] = __floats2half2_rn(acc[i][2 * j], acc[i][2 * j + 1]);
            }
        }
        __syncthreads();

        // ---- phase 3: half-dot scan (two waves, separate SIMDs); exp2/rcp gates ----
        if (wave < 2) {
            const int dir = wave;
            const __half* xp = xph + dir * (S_ * XPH_ST);
            float* sq = seqb + dir * NU + (lane & 31);
            const int stp = dir ? -1 : 1;
            int s = dir ? (S_ - 1) : 0;
            const bool wl = (lane < 32);
            const bool fix = (b4 != b5);
            float xz = (float)xp[s * XPH_ST + ud];
            float xr = (float)xp[s * XPH_ST + 32 + ud];
            float xh = (float)xp[s * XPH_ST + 64 + ud];
            for (int st = 0; st < S_; ++st) {
                float nz = 0.f, nr = 0.f, nh = 0.f;
                if (st < S_ - 1) {
                    const int sn = s + stp;
                    nz = (float)xp[sn * XPH_ST + ud];
                    nr = (float)xp[sn * XPH_ST + 32 + ud];
                    nh = (float)xp[sn * XPH_ST + 64 + ud];
                }
                // row-local butterfly: ro[m] = (h[BB + v16^ex[m]], h[BB + v16^ey[m]])
                v2f ro[8];
                ro[0].x = h_store;                ro[0].y = dppf<DPP_X1>(h_store);
                ro[1].x = dppf<DPP_X2>(ro[0].x);  ro[1].y = dppf<DPP_X2>(ro[0].y);
                ro[2].x = dppf<DPP_X7>(ro[0].x);  ro[2].y = dppf<DPP_X7>(ro[0].y);
                ro[3].x = dppf<DPP_X7>(ro[1].x);  ro[3].y = dppf<DPP_X7>(ro[1].y);
                ro[4].x = dppf<DPP_X15>(ro[0].x); ro[4].y = dppf<DPP_X15>(ro[0].y);
                ro[5].x = dppf<DPP_X15>(ro[1].x); ro[5].y = dppf<DPP_X15>(ro[1].y);
                ro[6].x = dppf<DPP_X15>(ro[2].x); ro[6].y = dppf<DPP_X15>(ro[2].y);
                ro[7].x = dppf<DPP_X15>(ro[3].x); ro[7].y = dppf<DPP_X15>(ro[3].y);

                // half-dots (16 terms); bias/x pre-halved (partner adds same)
                v2f aza = v2f{0.5f * xz + rbz2, 0.f}, azb = v2f{0.f, 0.f};
                v2f ara = v2f{0.5f * xr + rbr2, 0.f}, arb = v2f{0.f, 0.f};
                v2f aha = v2f{rbh2, 0.f},             ahb = v2f{0.f, 0.f};
                #pragma unroll
                for (int m = 0; m < 4; ++m) {
                    pkfma(aza, ro[m], wz[m]);      pkfma(azb, ro[m + 4], wz[m + 4]);
                    pkfma(ara, ro[m], wr_[m]);     pkfma(arb, ro[m + 4], wr_[m + 4]);
                    pkfma(aha, ro[m], wh[m]);      pkfma(ahb, ro[m + 4], wh[m + 4]);
                }
                v2f azs = aza + azb, ars = ara + arb, ahs = aha + ahb;
                const float pz = pairsum16(azs.x + azs.y);
                const float pr = pairsum16(ars.x + ars.y);
                const float ph = pairsum16(ahs.x + ahs.y);

                // exp2-based gates, raw rcp (no IEEE divide) — K1/K2 pre-folded
                const float z  = __builtin_amdgcn_rcpf(1.0f + __builtin_amdgcn_exp2f(-pz));
                const float r  = __builtin_amdgcn_rcpf(1.0f + __builtin_amdgcn_exp2f(-pr));
                const float tt = xh + r * ph;
                const float et = __builtin_amdgcn_exp2f(-tt);
                const float hh = (1.0f - et) * __builtin_amdgcn_rcpf(1.0f + et);
                const float hn_raw = hh + z * (h_dot - hh);
                h_dot = hn_raw;
                // placement: rows with b4!=b5 take the l^32 duplicate
                uv2 s32 = __builtin_amdgcn_permlane32_swap(
                    __float_as_uint(hn_raw), __float_as_uint(hn_raw), false, false);
                const float v32 = wl ? __uint_as_float(s32.y) : __uint_as_float(s32.x);
                h_store = fix ? v32 : hn_raw;
                if (wl) sq[s * SEQ_ST] = h_store;
                s += stp; xz = nz; xr = nr; xh = nh;
            }
        }
        __syncthreads();
    }

    // ---- final h + classifier ----
    if (wave < 2 && lane < 32) (wave ? hbb : hbf)[lane & 31] = h_store;
    __syncthreads();
    if (t == 0) {
        float l0 = b_cls[0], l1 = b_cls[1];
        for (int j = 0; j < NU; ++j) {
            const float hf = hbf[j], hk = hbb[j];
            l0 += hf * W_cls[4 * j]     + hk * W_cls[4 * j + 2];
            l1 += hf * W_cls[4 * j + 1] + hk * W_cls[4 * j + 3];
        }
        const float m = fmaxf(l0, l1);
        const float e0 = __expf(l0 - m), e1 = __expf(l1 - m);
        const float inv = 1.0f / (e0 + e1);
        out[b * 2 + 0] = e0 * inv;
        out[b * 2 + 1] = e1 * inv;
    }
}

extern "C" void kernel_launch(void* const* d_in, const int* in_sizes, int n_in,
                              void* d_out, int out_size, void* d_ws, size_t ws_size,
                              hipStream_t stream) {
    const float* xs    = (const float*)d_in[0];
    const float* W_lin = (const float*)d_in[1];
    const float* b_lin = (const float*)d_in[2];
    const float* ln_g  = (const float*)d_in[3];
    const float* ln_b  = (const float*)d_in[4];
    const float* Wk_f  = (const float*)d_in[5];
    const float* Wr_f  = (const float*)d_in[6];
    const float* b_f   = (const float*)d_in[7];
    const float* Wk_b  = (const float*)d_in[8];
    const float* Wr_b  = (const float*)d_in[9];
    const float* b_b   = (const float*)d_in[10];
    const float* W_cls = (const float*)d_in[11];
    const float* b_cls = (const float*)d_in[12];
    float* out = (float*)d_out;

    __half* lin_all = (__half*)d_ws;   // 13*4096*64 fp16 = 6,815,744 B

    // floats: seqb 8704 + xt2 4128 + wk2 6400 + xph 12800 + hb 64 = 32,096 -> 128,384 B
    const int smem = (8704 + 4128 + 6400 + 12800 + 64) * (int)sizeof(float);
    (void)hipFuncSetAttribute((const void*)chain_kernel,
                              hipFuncAttributeMaxDynamicSharedMemorySize, smem);

    lin2_kernel<<<L_ * B_, 512, 0, stream>>>(xs, W_lin, b_lin, lin_all);

    chain_kernel<<<B_, 512, smem, stream>>>(
        lin_all, Wr_f, b_f, Wr_b, b_b, Wk_f, Wk_b, ln_g, ln_b, W_cls, b_cls, out);
}